// Round 1
// 159.830 us; speedup vs baseline: 1.0584x; 1.0584x over previous
//
#include <hip/hip_runtime.h>
#include <hip/hip_bf16.h>

typedef __hip_bfloat16 bf16;
typedef __attribute__((ext_vector_type(8))) short short8;
typedef __attribute__((ext_vector_type(4))) float float4v;

#define NN   768
#define NEPS 767

// ---- converted fp32 constants ----
#define C_NUC   0
#define C_F     2304
#define C_MP1W0 2656
#define C_MP1B0 5728
#define C_MP1W1 5760
#define C_MP1B1 6784
#define C_UP1W0 6816
#define C_UP1B0 10912
#define C_UP1W1 10976
#define C_UP1B1 15072
#define C_MP2W0 15136
#define C_MP2B0 20256
#define C_MP2W1 20288
#define C_MP2B1 21312
#define C_UP2W0 21344
#define C_UP2B0 27488
#define C_UP2W1 27552
#define C_UP2B1 31648
#define C_NOW0  31712
#define C_NOB0  32192
#define C_NOW1  32195
#define C_NOEMB 32204
#define C_GOW0  32234
#define C_GOB0  32394
#define C_GOW1  32395
#define C_GOB1  32396
__device__ __align__(16) float g_c[32400];

// ---- fp32 scratch ----
#define OFF_EMB0 0
#define OFF_SA1  24576
#define OFF_SB1  49152
#define OFF_EMB1 73728
#define OFF_SA2  122880
#define OFF_SB2  147456
__device__ float g_ws[172032];
__device__ float g_agg[640];     // 4 replicas x 160
__device__ int   g_cnt;
__device__ int   g_isf;

struct Ptrs { const void* p[28]; };

__device__ __forceinline__ float b2f(bf16 v){ return __bfloat162float(v); }
__device__ __forceinline__ float LD(const void* p, int i, int f32){
  return f32 ? ((const float*)p)[i] : b2f(((const bf16*)p)[i]);
}
__device__ __forceinline__ int detect_f32(const void* f){
  float v = ((const float*)f)[0];
  return (fabsf(v - 3.14159265f) < 0.01f) ? 1 : 0;
}
__device__ __forceinline__ float fast_rcp(float x){ return __builtin_amdgcn_rcpf(x); }
__device__ __forceinline__ float silu_f(float p){ return p * fast_rcp(1.f + __expf(-p)); }
__device__ __forceinline__ unsigned short rne_bf16(float x){
  unsigned int b = __float_as_uint(x);
  return (unsigned short)((b + 0x7fffu + ((b >> 16) & 1u)) >> 16);
}
__device__ __forceinline__ unsigned int cvtpk_bf16(float lo, float hi){
  unsigned int r;
  asm("v_cvt_pk_bf16_f32 %0, %1, %2" : "=v"(r) : "v"(lo), "v"(hi));
  return r;
}
__device__ __forceinline__ void cv(const void* p, int off, int sz, int gt, int isf){
  for (int i = gt; i < sz; i += 96*256) g_c[off + i] = LD(p, i, isf);
}

// ---------------- K1: convert inputs to fp32 + emb0/SA1/SB1 prep ----------------
__launch_bounds__(256)
__global__ void k_conv_prep(Ptrs P, const int* __restrict__ charges){
  int t = threadIdx.x;
  int gt = blockIdx.x*256 + t;
  int isf = detect_f32(P.p[2]);
  if (gt == 0){ g_isf = isf; g_cnt = 0; }
  if (gt < 640) g_agg[gt] = 0.f;

  cv(P.p[0],  C_NUC,   2304, gt, isf);
  cv(P.p[2],  C_F,     32,   gt, isf);
  cv(P.p[4],  C_MP1W0, 3072, gt, isf);
  cv(P.p[5],  C_MP1B0, 32,   gt, isf);
  cv(P.p[6],  C_MP1W1, 1024, gt, isf);
  cv(P.p[7],  C_MP1B1, 32,   gt, isf);
  cv(P.p[8],  C_UP1W0, 4096, gt, isf);
  cv(P.p[9],  C_UP1B0, 64,   gt, isf);
  cv(P.p[10], C_UP1W1, 4096, gt, isf);
  cv(P.p[11], C_UP1B1, 64,   gt, isf);
  cv(P.p[12], C_MP2W0, 5120, gt, isf);
  cv(P.p[13], C_MP2B0, 32,   gt, isf);
  cv(P.p[14], C_MP2W1, 1024, gt, isf);
  cv(P.p[15], C_MP2B1, 32,   gt, isf);
  cv(P.p[16], C_UP2W0, 6144, gt, isf);
  cv(P.p[17], C_UP2B0, 64,   gt, isf);
  cv(P.p[18], C_UP2W1, 4096, gt, isf);
  cv(P.p[19], C_UP2B1, 64,   gt, isf);
  cv(P.p[20], C_NOW0,  480,  gt, isf);
  cv(P.p[21], C_NOB0,  3,    gt, isf);
  cv(P.p[22], C_NOW1,  9,    gt, isf);
  cv(P.p[23], C_NOEMB, 30,   gt, isf);
  cv(P.p[24], C_GOW0,  160,  gt, isf);
  cv(P.p[25], C_GOB0,  1,    gt, isf);
  cv(P.p[26], C_GOW1,  1,    gt, isf);
  cv(P.p[27], C_GOB1,  1,    gt, isf);

  __shared__ float w0L[2048];
  __shared__ float rowL[8][32];
  for (int idx = t; idx < 2048; idx += 256) w0L[idx] = LD(P.p[4], idx, isf);
  int nd = t >> 5, col = t & 31;
  int node = blockIdx.x*8 + nd;
  int ch = charges[node];
  float v = LD(P.p[3], ch*32 + col, isf);
  g_ws[OFF_EMB0 + node*32 + col] = v;
  rowL[nd][col] = v;
  __syncthreads();
  float sa = 0.f, sb = 0.f;
  #pragma unroll
  for (int k = 0; k < 32; k++){
    float rv = rowL[nd][k];
    sa = fmaf(rv, w0L[k*32 + col],      sa);
    sb = fmaf(rv, w0L[(32+k)*32 + col], sb);
  }
  g_ws[OFF_SA1 + node*32 + col] = sa;
  g_ws[OFF_SB1 + node*32 + col] = sb;
}

// ---------------- K2: edge pass L1 (8 waves, 6 tiles/wave) + fused update-1 ----------------
__launch_bounds__(512)
__global__ void k_edge1(){
  __shared__ __align__(16) float pos[NN*3];
  __shared__ __align__(16) float w1L[1024];
  __shared__ float wsum[8][32];
  __shared__ float hsumL[32];
  __shared__ float msgL[32];
  __shared__ float catU[64], hU[64], e1U[64];
  __shared__ float part[512];

  int i = blockIdx.x, t = threadIdx.x;
  int w = t >> 6, lane = t & 63, q = lane >> 4, c = lane & 15;

  {
    const float4* src = (const float4*)(g_c + C_NUC);
    float4* dst = (float4*)pos;
    for (int idx = t; idx < 576; idx += 512) dst[idx] = src[idx];
    if (t < 256) ((float4*)w1L)[t] = ((const float4*)(g_c + C_MP1W1))[t];
  }
  const float* SA = g_ws + OFF_SA1;
  const float* SB = g_ws + OFF_SB1;
  short8 bfr0, bfr1;
  #pragma unroll
  for (int j = 0; j < 8; j++){
    int row = q*8 + j;
    bfr0[j] = (short)rne_bf16(g_c[C_MP1W0 + 2048 + row*32 + c]);
    bfr1[j] = (short)rne_bf16(g_c[C_MP1W0 + 2048 + row*32 + 16 + c]);
  }
  float preB0 = SA[i*32 + c]      + g_c[C_MP1B0 + c];
  float preB1 = SA[i*32 + 16 + c] + g_c[C_MP1B0 + 16 + c];
  float fj[8];
  #pragma unroll
  for (int j = 0; j < 8; j++) fj[j] = g_c[C_F + q*8 + j] * 0.1f;
  __syncthreads();

  float px = pos[i*3], py = pos[i*3+1], pz = pos[i*3+2];

  // 6 tiles per wave: batch distances up front (independent chains)
  float xs[6], scv[6];
  #pragma unroll
  for (int s = 0; s < 6; s++){
    int el = (w + s*8)*16 + c;
    int ela = (el < NEPS) ? el : 0;
    int r = ela + (ela >= i);
    float dx = px - pos[r*3], dy = py - pos[r*3+1], dz = pz - pos[r*3+2];
    float d = sqrtf(fmaf(dx, dx, fmaf(dy, dy, dz*dz)));
    xs[s] = d + 1e-8f;
    scv[s] = 0.44721359549995793f * fast_rcp(xs[s]);
  }

  float sum0 = 0.f, sum1 = 0.f;
  #pragma unroll
  for (int s = 0; s < 6; s++){
    int tl = w + s*8;
    // SB prefetch issued before the sin chain (latency cover)
    float sb0[4], sb1[4];
    #pragma unroll
    for (int p = 0; p < 4; p++){
      int el2 = tl*16 + q*4 + p;
      int e2a = (el2 < NEPS) ? el2 : 0;
      int r2 = e2a + (e2a >= i);
      sb0[p] = SB[r2*32 + c];
      sb1[p] = SB[r2*32 + 16 + c];
    }
    float sv[8];
    #pragma unroll
    for (int j = 0; j < 8; j++) sv[j] = scv[s] * __sinf(fj[j]*xs[s]);
    union { short8 s8; unsigned int u[4]; } afu;
    #pragma unroll
    for (int h = 0; h < 4; h++) afu.u[h] = cvtpk_bf16(sv[2*h], sv[2*h+1]);
    short8 af = afu.s8;
    float4v z = {0.f, 0.f, 0.f, 0.f};
    float4v a0 = __builtin_amdgcn_mfma_f32_16x16x32_bf16(af, bfr0, z, 0, 0, 0);
    float4v a1 = __builtin_amdgcn_mfma_f32_16x16x32_bf16(af, bfr1, z, 0, 0, 0);
    #pragma unroll
    for (int p = 0; p < 4; p++){
      int el2 = tl*16 + q*4 + p;
      if (el2 < NEPS){
        sum0 += silu_f(a0[p] + preB0 + sb0[p]);
        sum1 += silu_f(a1[p] + preB1 + sb1[p]);
      }
    }
  }
  sum0 += __shfl_xor(sum0, 16); sum0 += __shfl_xor(sum0, 32);
  sum1 += __shfl_xor(sum1, 16); sum1 += __shfl_xor(sum1, 32);
  if (lane < 16){ wsum[w][lane] = sum0; wsum[w][16 + lane] = sum1; }
  __syncthreads();
  if (t < 32) hsumL[t] = wsum[0][t] + wsum[1][t] + wsum[2][t] + wsum[3][t]
                       + wsum[4][t] + wsum[5][t] + wsum[6][t] + wsum[7][t];
  __syncthreads();
  if (t < 32){
    float y = 0.f;
    #pragma unroll
    for (int m = 0; m < 32; m++) y = fmaf(hsumL[m], w1L[m*32 + t], y);
    msgL[t] = y * (1.f/767.f) + g_c[C_MP1B1 + t];
  }

  if (t < 32){
    catU[t] = g_ws[OFF_EMB0 + i*32 + t];
    catU[32 + t] = msgL[t];
  }
  __syncthreads();

  // update MLP 1: layer A (64x64), 512 threads -> 8 partials of 8 k's
  int g = t >> 6, col = t & 63;
  {
    const float* w0 = g_c + C_UP1W0;
    float p0 = 0.f;
    #pragma unroll
    for (int j = 0; j < 8; j++){ int k = g*8 + j; p0 = fmaf(catU[k], w0[k*64 + col], p0); }
    part[t] = p0;
  }
  __syncthreads();
  if (t < 64){
    float s = part[t] + part[64+t] + part[128+t] + part[192+t]
            + part[256+t] + part[320+t] + part[384+t] + part[448+t];
    hU[t] = silu_f(g_c[C_UP1B0 + t] + s);
  }
  __syncthreads();
  {
    const float* w1u = g_c + C_UP1W1;
    float p1 = 0.f;
    #pragma unroll
    for (int j = 0; j < 8; j++){ int k = g*8 + j; p1 = fmaf(hU[k], w1u[k*64 + col], p1); }
    part[t] = p1;
  }
  __syncthreads();
  if (t < 64){
    float s = part[t] + part[64+t] + part[128+t] + part[192+t]
            + part[256+t] + part[320+t] + part[384+t] + part[448+t];
    float y = g_c[C_UP1B1 + t] + s;
    e1U[t] = y;
    g_ws[OFF_EMB1 + i*64 + t] = y;
  }
  __syncthreads();
  // MP2 pre: SA2/SB2 = e1U @ MP2W0 rows [0:64] / [64:128]
  {
    int oc = t & 63;                  // 0..31 -> SA2 cols, 32..63 -> SB2 cols
    const float* m2 = g_c + C_MP2W0;
    float p2 = 0.f;
    #pragma unroll
    for (int j = 0; j < 8; j++){
      int k = g*8 + j;
      p2 = fmaf(e1U[k], m2[((oc >> 5)*64 + k)*32 + (oc & 31)], p2);
    }
    part[t] = p2;
  }
  __syncthreads();
  if (t < 64){
    float s = part[t] + part[64+t] + part[128+t] + part[192+t]
            + part[256+t] + part[320+t] + part[384+t] + part[448+t];
    if ((t >> 5) == 0) g_ws[OFF_SA2 + i*32 + (t & 31)] = s;
    else               g_ws[OFF_SB2 + i*32 + (t & 31)] = s;
  }
}

// ---------------- K3: edge pass L2 (recomputes RBF) + fused update-2 + outputs ----------------
__launch_bounds__(512)
__global__ void k_edge2(const int* __restrict__ charges, void* __restrict__ out){
  __shared__ __align__(16) float pos[NN*3];
  __shared__ __align__(16) float w1L[1024];
  __shared__ float wsum[8][32];
  __shared__ float hsumL[32];
  __shared__ float msgL[32];
  __shared__ float catU[96], hU[64], aggL[160], noL[522], h3L[3];
  __shared__ float part[512];
  __shared__ int lastL;

  int i = blockIdx.x, t = threadIdx.x;
  int w = t >> 6, lane = t & 63, q = lane >> 4, c = lane & 15;

  {
    const float4* src = (const float4*)(g_c + C_NUC);
    float4* dst = (float4*)pos;
    for (int idx = t; idx < 576; idx += 512) dst[idx] = src[idx];
    if (t < 256) ((float4*)w1L)[t] = ((const float4*)(g_c + C_MP2W1))[t];
  }
  const float* SA = g_ws + OFF_SA2;
  const float* SB = g_ws + OFF_SB2;
  short8 bfr0, bfr1;
  #pragma unroll
  for (int j = 0; j < 8; j++){
    int row = q*8 + j;
    bfr0[j] = (short)rne_bf16(g_c[C_MP2W0 + 4096 + row*32 + c]);
    bfr1[j] = (short)rne_bf16(g_c[C_MP2W0 + 4096 + row*32 + 16 + c]);
  }
  float preB0 = SA[i*32 + c]      + g_c[C_MP2B0 + c];
  float preB1 = SA[i*32 + 16 + c] + g_c[C_MP2B0 + 16 + c];
  float fj[8];
  #pragma unroll
  for (int j = 0; j < 8; j++) fj[j] = g_c[C_F + q*8 + j] * 0.1f;
  __syncthreads();

  float px = pos[i*3], py = pos[i*3+1], pz = pos[i*3+2];

  float xs[6], scv[6];
  #pragma unroll
  for (int s = 0; s < 6; s++){
    int el = (w + s*8)*16 + c;
    int ela = (el < NEPS) ? el : 0;
    int r = ela + (ela >= i);
    float dx = px - pos[r*3], dy = py - pos[r*3+1], dz = pz - pos[r*3+2];
    float d = sqrtf(fmaf(dx, dx, fmaf(dy, dy, dz*dz)));
    xs[s] = d + 1e-8f;
    scv[s] = 0.44721359549995793f * fast_rcp(xs[s]);
  }

  float sum0 = 0.f, sum1 = 0.f;
  #pragma unroll
  for (int s = 0; s < 6; s++){
    int tl = w + s*8;
    float sb0[4], sb1[4];
    #pragma unroll
    for (int p = 0; p < 4; p++){
      int el2 = tl*16 + q*4 + p;
      int e2a = (el2 < NEPS) ? el2 : 0;
      int r2 = e2a + (e2a >= i);
      sb0[p] = SB[r2*32 + c];
      sb1[p] = SB[r2*32 + 16 + c];
    }
    float sv[8];
    #pragma unroll
    for (int j = 0; j < 8; j++) sv[j] = scv[s] * __sinf(fj[j]*xs[s]);
    union { short8 s8; unsigned int u[4]; } afu;
    #pragma unroll
    for (int h = 0; h < 4; h++) afu.u[h] = cvtpk_bf16(sv[2*h], sv[2*h+1]);
    short8 af = afu.s8;
    float4v z = {0.f, 0.f, 0.f, 0.f};
    float4v a0 = __builtin_amdgcn_mfma_f32_16x16x32_bf16(af, bfr0, z, 0, 0, 0);
    float4v a1 = __builtin_amdgcn_mfma_f32_16x16x32_bf16(af, bfr1, z, 0, 0, 0);
    #pragma unroll
    for (int p = 0; p < 4; p++){
      int el2 = tl*16 + q*4 + p;
      if (el2 < NEPS){
        sum0 += silu_f(a0[p] + preB0 + sb0[p]);
        sum1 += silu_f(a1[p] + preB1 + sb1[p]);
      }
    }
  }
  sum0 += __shfl_xor(sum0, 16); sum0 += __shfl_xor(sum0, 32);
  sum1 += __shfl_xor(sum1, 16); sum1 += __shfl_xor(sum1, 32);
  if (lane < 16){ wsum[w][lane] = sum0; wsum[w][16 + lane] = sum1; }
  __syncthreads();
  if (t < 32) hsumL[t] = wsum[0][t] + wsum[1][t] + wsum[2][t] + wsum[3][t]
                       + wsum[4][t] + wsum[5][t] + wsum[6][t] + wsum[7][t];
  __syncthreads();
  if (t < 32){
    float y = 0.f;
    #pragma unroll
    for (int m = 0; m < 32; m++) y = fmaf(hsumL[m], w1L[m*32 + t], y);
    msgL[t] = y * (1.f/767.f) + g_c[C_MP2B1 + t];
  }

  if (t < 64) catU[t] = g_ws[OFF_EMB1 + i*64 + t];
  if (t < 32){ catU[64 + t] = msgL[t]; aggL[t] = g_ws[OFF_EMB0 + i*32 + t]; }
  for (int idx = t; idx < 522; idx += 512) noL[idx] = g_c[C_NOW0 + idx];
  __syncthreads();

  // update MLP 2: layer A (96x64), 512 threads -> 8 partials of 12 k's
  int g = t >> 6, col = t & 63;
  {
    const float* w0 = g_c + C_UP2W0;
    float p0 = 0.f;
    #pragma unroll
    for (int j = 0; j < 12; j++){ int k = g*12 + j; p0 = fmaf(catU[k], w0[k*64 + col], p0); }
    part[t] = p0;
  }
  __syncthreads();
  if (t < 64){
    float s = part[t] + part[64+t] + part[128+t] + part[192+t]
            + part[256+t] + part[320+t] + part[384+t] + part[448+t];
    hU[t] = silu_f(g_c[C_UP2B0 + t] + s);
  }
  __syncthreads();
  {
    const float* w1u = g_c + C_UP2W1;
    float p1 = 0.f;
    #pragma unroll
    for (int j = 0; j < 8; j++){ int k = g*8 + j; p1 = fmaf(hU[k], w1u[k*64 + col], p1); }
    part[t] = p1;
  }
  __syncthreads();
  if (t < 64){
    float s = part[t] + part[64+t] + part[128+t] + part[192+t]
            + part[256+t] + part[320+t] + part[384+t] + part[448+t];
    float y = g_c[C_UP2B1 + t] + s;
    float e2 = catU[t] + y;
    aggL[32 + t] = catU[t];
    aggL[96 + t] = e2;
  }
  __syncthreads();
  if (t < 48){
    int chunk = t / 3, c3 = t - chunk*3;
    float p = 0.f;
    #pragma unroll
    for (int j = 0; j < 10; j++){ int k = chunk*10 + j; p = fmaf(aggL[k], noL[k*3 + c3], p); }
    part[t] = p;
  }
  __syncthreads();
  if (t < 3){
    float p = noL[480 + t];
    #pragma unroll
    for (int ch = 0; ch < 16; ch++) p += part[ch*3 + t];
    h3L[t] = silu_f(p);
  }
  __syncthreads();
  if (t < 3){
    float o = 0.f;
    #pragma unroll
    for (int m = 0; m < 3; m++) o = fmaf(h3L[m], noL[483 + m*3 + t], o);
    o += noL[492 + charges[i]*3 + t];
    if (g_isf) ((float*)out)[i*3 + t] = o;
    else       ((bf16*)out)[i*3 + t] = __float2bfloat16(o);
  }
  // global aggregation (no fence: __syncthreads drains vmcnt -> atomics performed)
  if (t < 160) atomicAdd(&g_agg[(i & 3)*160 + t], aggL[t]);
  __syncthreads();
  if (t == 0) lastL = (atomicAdd(&g_cnt, 1) == NN - 1) ? 1 : 0;
  __syncthreads();
  if (lastL){
    float v = 0.f;
    if (t < 160){
      float s = atomicAdd(&g_agg[t], 0.f) + atomicAdd(&g_agg[160 + t], 0.f)
              + atomicAdd(&g_agg[320 + t], 0.f) + atomicAdd(&g_agg[480 + t], 0.f);
      v = s * (1.f/768.f) * g_c[C_GOW0 + t];
    }
    part[t] = v;
    __syncthreads();
    if (t == 0){
      float tot = 0.f;
      for (int k = 0; k < 160; k++) tot += part[k];
      float h = silu_f(tot + g_c[C_GOB0]);
      float go = h * g_c[C_GOW1] + g_c[C_GOB1];
      if (g_isf) ((float*)out)[2304] = go;
      else       ((bf16*)out)[2304] = __float2bfloat16(go);
    }
  }
}

extern "C" void kernel_launch(void* const* d_in, const int* in_sizes, int n_in,
                              void* d_out, int out_size, void* d_ws, size_t ws_size,
                              hipStream_t stream) {
  Ptrs P;
  for (int k = 0; k < 28; k++) P.p[k] = d_in[k];
  const int* charges = (const int*)d_in[1];

  k_conv_prep<<<96, 256, 0, stream>>>(P, charges);
  k_edge1<<<NN, 512, 0, stream>>>();
  k_edge2<<<NN, 512, 0, stream>>>(charges, d_out);
}